// Round 17
// baseline (29.625 us; speedup 1.0000x reference)
//
#include <hip/hip_runtime.h>
#include <hip/hip_bf16.h>

#define BATCH 8192
#define DDIM 512
#define FDIM 64
#define KD 64

typedef __attribute__((ext_vector_type(8))) short short8;
typedef __attribute__((ext_vector_type(4))) float f32x4;

static __device__ __forceinline__ unsigned short f2bf(float f) {
    __hip_bfloat16 h = __float2bfloat16(f);
    return *reinterpret_cast<unsigned short*>(&h);
}
static __device__ __forceinline__ float bf2f(unsigned short s) {
    union { unsigned int u; float f; } c;
    c.u = ((unsigned int)s) << 16;
    return c.f;
}

static __device__ __forceinline__ void gll16(const void* g, void* l) {
    __builtin_amdgcn_global_load_lds(
        (const __attribute__((address_space(1))) void*)g,
        (__attribute__((address_space(3))) void*)l, 16, 0, 0);
}

// ---------------- W^T (bf16, N-major) + x->bf16 + zero out ----------------
// Grid (iq=4, j=512). Block (j,iq): WT[j, iq*128 .. iq*128+128) and one
// 2048-float slice of x (2048 blocks x 2048 floats = 4.19M, exact).
__global__ __launch_bounds__(256) void w_kernel(const float* __restrict__ kern,
                                                const int* __restrict__ fd,
                                                const float* __restrict__ x,
                                                unsigned short* __restrict__ WT,
                                                unsigned short* __restrict__ xb,
                                                float* __restrict__ out) {
    const int iq = blockIdx.x;        // 0..3
    const int j = blockIdx.y;         // 0..511
    const int tid = threadIdx.x;

    // ---- x -> bf16: one 2048-float slice, 8 floats/thread ----
    {
        const size_t base = ((size_t)j * 4 + iq) * 2048;
        const float4* X4 = reinterpret_cast<const float4*>(x + base);
        float4 p = X4[tid * 2];
        float4 q = X4[tid * 2 + 1];
        short8 v;
        v[0] = (short)f2bf(p.x); v[1] = (short)f2bf(p.y);
        v[2] = (short)f2bf(p.z); v[3] = (short)f2bf(p.w);
        v[4] = (short)f2bf(q.x); v[5] = (short)f2bf(q.y);
        v[6] = (short)f2bf(q.z); v[7] = (short)f2bf(q.w);
        *reinterpret_cast<short8*>(xb + base + tid * 8) = v;
    }

    if (iq == 0 && tid < 16) out[j * 16 + tid] = 0.f;   // zero out (runs before quad)

    const int ibase = iq * 128;
    if (ibase >= j) {
        // whole i-range >= j: exact zeros
        if (tid < 16) {
            short8 z = {};
            *reinterpret_cast<short8*>(WT + (size_t)j * DDIM + ibase + tid * 8) = z;
        }
        return;
    }

    __shared__ float Bv[FDIM * KD];   // kernel[j,:,:]  (16 KB)
    __shared__ int fds[128];          // fd[ibase .. ibase+128)
    {
        const float4* src = reinterpret_cast<const float4*>(kern + (size_t)j * FDIM * KD);
        float4* dst = reinterpret_cast<float4*>(Bv);
#pragma unroll
        for (int u = 0; u < 4; ++u) dst[u * 256 + tid] = src[u * 256 + tid];
        if (tid < 128) fds[tid] = fd[ibase + tid];
    }
    const int fdj = fd[j];
    __syncthreads();

    const int g = tid >> 4;    // 16-lane group -> one i per iteration
    const int gl = tid & 15;   // lane over k (4 floats each)

#pragma unroll 8
    for (int it = 0; it < 8; ++it) {
        const int i = ibase + it * 16 + g;
        float s = 0.f;
        if (i < j) {
            float4 a = *reinterpret_cast<const float4*>(kern + ((size_t)i * FDIM + fdj) * KD + gl * 4);
            float4 b = *reinterpret_cast<const float4*>(Bv + fds[it * 16 + g] * KD + gl * 4);
            s = a.x * b.x + a.y * b.y + a.z * b.z + a.w * b.w;
        }
#pragma unroll
        for (int off = 1; off < 16; off <<= 1) s += __shfl_xor(s, off);
        if (gl == 0) WT[(size_t)j * DDIM + i] = f2bf(s);
    }
}

// ---------------- fused  out[b] = x[b,:] @ Wm @ x[b,:]  (MFMA bf16) ----------------
// Balanced triangle repacked to 1024 blocks (exactly 4/CU, one residency round):
// per m-panel, 8 blocks cover the 10 k-chunk units — nb=0..2 as 4-step blocks,
// nb=3's four chunks merged pairwise into two 8-step blocks.
#define BM 64
#define BN 128
#define BK 32

__global__ __launch_bounds__(256, 4) void quad_kernel(const unsigned short* __restrict__ xb,
                                                      const unsigned short* __restrict__ WT,
                                                      float* __restrict__ out) {
    __shared__ unsigned short As[2][BM * BK];   // 2 x 4 KB, linear [row][k]
    __shared__ unsigned short Bs[2][BN * BK];   // 2 x 8 KB, linear [col][k]

    const int tid = threadIdx.x;
    const int lane = tid & 63;
    const int w = tid >> 6;
    const int wm = w >> 1, wn = w & 1;
    const int ln = lane & 15, l4 = lane >> 4;

    // id = cp*128 + m : m-sharing blocks are ≡ m (mod 8) -> same XCD L2.
    const int mb = blockIdx.x & 127;
    const int cp = blockIdx.x >> 7;           // 0..7
    const int nb = (cp >= 1) + (cp >= 3) + (cp >= 6);
    const int chunk = cp - nb * (nb + 1) / 2; // within-panel chunk unit
    const int ks = (nb == 3) ? 8 : 4;         // k-steps this block owns
    const int kbase = chunk * ((nb == 3) ? 256 : 128);
    const int nbase = nb * BN;
    const int mbase = mb * BM;

    f32x4 acc[2][4] = {};

    const int srow = tid >> 2;       // 0..63
    const int sk = (tid & 3) * 8;    // k offset (elements) of this thread's 16B

    auto stage = [&](int kk, int buf) {
        gll16(xb + (size_t)(mbase + srow) * DDIM + kk + sk, &As[buf][tid * 8]);
        gll16(WT + (size_t)(nbase + srow) * DDIM + kk + sk, &Bs[buf][tid * 8]);
        gll16(WT + (size_t)(nbase + 64 + srow) * DDIM + kk + sk, &Bs[buf][2048 + tid * 8]);
    };
    auto compute = [&](int buf) {
        short8 a[2], b[4];
#pragma unroll
        for (int m = 0; m < 2; ++m) {
            int row = wm * 32 + m * 16 + ln;
            a[m] = *reinterpret_cast<const short8*>(&As[buf][row * BK + l4 * 8]);
        }
#pragma unroll
        for (int n = 0; n < 4; ++n) {
            int col = wn * 64 + n * 16 + ln;
            b[n] = *reinterpret_cast<const short8*>(&Bs[buf][col * BK + l4 * 8]);
        }
#pragma unroll
        for (int m = 0; m < 2; ++m)
#pragma unroll
            for (int n = 0; n < 4; ++n)
                acc[m][n] = __builtin_amdgcn_mfma_f32_16x16x32_bf16(a[m], b[n], acc[m][n], 0, 0, 0);
    };

    stage(kbase, 0);
    __syncthreads();                       // buf0 ready
    for (int t = 0; t < ks; ++t) {
        if (t + 1 < ks) stage(kbase + (t + 1) * BK, (t + 1) & 1);  // next tile in flight
        compute(t & 1);
        __syncthreads();                   // next buf ready / current buf free
    }

    // epilogue: out[row] += sum_col y_partial[row][col] * xb[row][col]
#pragma unroll
    for (int m = 0; m < 2; ++m) {
#pragma unroll
        for (int q = 0; q < 4; ++q) {
            int grow = mbase + wm * 32 + m * 16 + l4 * 4 + q;   // C/D: row=(lane>>4)*4+reg
            float s = 0.f;
#pragma unroll
            for (int n = 0; n < 4; ++n) {
                int gcol = nbase + wn * 64 + n * 16 + ln;        // C/D: col=lane&15
                s += acc[m][n][q] * bf2f(xb[(size_t)grow * DDIM + gcol]);
            }
#pragma unroll
            for (int off = 1; off < 16; off <<= 1)
                s += __shfl_xor(s, off, 64);
            if (ln == 0) atomicAdd(out + grow, s);
        }
    }
}

extern "C" void kernel_launch(void* const* d_in, const int* in_sizes, int n_in,
                              void* d_out, int out_size, void* d_ws, size_t ws_size,
                              hipStream_t stream) {
    const float* x = (const float*)d_in[0];
    const float* kern = (const float*)d_in[1];
    const int* fd = (const int*)d_in[2];
    float* out = (float*)d_out;

    unsigned short* WT = (unsigned short*)d_ws;                      // 512 KB
    unsigned short* xb = WT + (size_t)DDIM * DDIM;                   // 8 MB

    dim3 wgrid(4, DDIM);
    w_kernel<<<wgrid, 256, 0, stream>>>(kern, fd, x, WT, xb, out);
    quad_kernel<<<1024, 256, 0, stream>>>(xb, WT, out);
}

// Round 18
// 27.635 us; speedup vs baseline: 1.0720x; 1.0720x over previous
//
#include <hip/hip_runtime.h>
#include <hip/hip_bf16.h>

#define BATCH 8192
#define DDIM 512
#define FDIM 64
#define KD 64

typedef __attribute__((ext_vector_type(8))) short short8;
typedef __attribute__((ext_vector_type(4))) float f32x4;

static __device__ __forceinline__ unsigned short f2bf(float f) {
    __hip_bfloat16 h = __float2bfloat16(f);
    return *reinterpret_cast<unsigned short*>(&h);
}
static __device__ __forceinline__ float bf2f(unsigned short s) {
    union { unsigned int u; float f; } c;
    c.u = ((unsigned int)s) << 16;
    return c.f;
}

static __device__ __forceinline__ void gll16(const void* g, void* l) {
    __builtin_amdgcn_global_load_lds(
        (const __attribute__((address_space(1))) void*)g,
        (__attribute__((address_space(3))) void*)l, 16, 0, 0);
}

// ---------------- W^T (bf16, N-major) + x->bf16 + zero out ----------------
// Grid (iq=4, j=512). Block (j,iq): WT[j, iq*128 .. iq*128+128) and one
// 2048-float slice of x (2048 blocks x 2048 floats = 4.19M, exact).
__global__ __launch_bounds__(256) void w_kernel(const float* __restrict__ kern,
                                                const int* __restrict__ fd,
                                                const float* __restrict__ x,
                                                unsigned short* __restrict__ WT,
                                                unsigned short* __restrict__ xb,
                                                float* __restrict__ out) {
    const int iq = blockIdx.x;        // 0..3
    const int j = blockIdx.y;         // 0..511
    const int tid = threadIdx.x;

    // ---- x -> bf16: one 2048-float slice, 8 floats/thread ----
    {
        const size_t base = ((size_t)j * 4 + iq) * 2048;
        const float4* X4 = reinterpret_cast<const float4*>(x + base);
        float4 p = X4[tid * 2];
        float4 q = X4[tid * 2 + 1];
        short8 v;
        v[0] = (short)f2bf(p.x); v[1] = (short)f2bf(p.y);
        v[2] = (short)f2bf(p.z); v[3] = (short)f2bf(p.w);
        v[4] = (short)f2bf(q.x); v[5] = (short)f2bf(q.y);
        v[6] = (short)f2bf(q.z); v[7] = (short)f2bf(q.w);
        *reinterpret_cast<short8*>(xb + base + tid * 8) = v;
    }

    if (iq == 0 && tid < 16) out[j * 16 + tid] = 0.f;   // zero out (runs before quad)

    const int ibase = iq * 128;
    if (ibase >= j) {
        // whole i-range >= j: exact zeros
        if (tid < 16) {
            short8 z = {};
            *reinterpret_cast<short8*>(WT + (size_t)j * DDIM + ibase + tid * 8) = z;
        }
        return;
    }

    __shared__ float Bv[FDIM * KD];   // kernel[j,:,:]  (16 KB)
    __shared__ int fds[128];          // fd[ibase .. ibase+128)
    {
        const float4* src = reinterpret_cast<const float4*>(kern + (size_t)j * FDIM * KD);
        float4* dst = reinterpret_cast<float4*>(Bv);
#pragma unroll
        for (int u = 0; u < 4; ++u) dst[u * 256 + tid] = src[u * 256 + tid];
        if (tid < 128) fds[tid] = fd[ibase + tid];
    }
    const int fdj = fd[j];
    __syncthreads();

    const int g = tid >> 4;    // 16-lane group -> one i per iteration
    const int gl = tid & 15;   // lane over k (4 floats each)

#pragma unroll 8
    for (int it = 0; it < 8; ++it) {
        const int i = ibase + it * 16 + g;
        float s = 0.f;
        if (i < j) {
            float4 a = *reinterpret_cast<const float4*>(kern + ((size_t)i * FDIM + fdj) * KD + gl * 4);
            float4 b = *reinterpret_cast<const float4*>(Bv + fds[it * 16 + g] * KD + gl * 4);
            s = a.x * b.x + a.y * b.y + a.z * b.z + a.w * b.w;
        }
#pragma unroll
        for (int off = 1; off < 16; off <<= 1) s += __shfl_xor(s, off);
        if (gl == 0) WT[(size_t)j * DDIM + i] = f2bf(s);
    }
}

// ---------------- fused  out[b] = x[b,:] @ Wm @ x[b,:]  (MFMA bf16) ----------------
// r16 structure (1280 uniform 4-step blocks) at 5 blocks/CU: one residency round.
#define BM 64
#define BN 128
#define BK 32
#define KSTEPS 4

__global__ __launch_bounds__(256, 5) void quad_kernel(const unsigned short* __restrict__ xb,
                                                      const unsigned short* __restrict__ WT,
                                                      float* __restrict__ out) {
    __shared__ unsigned short As[2][BM * BK];   // 2 x 4 KB, linear [row][k]
    __shared__ unsigned short Bs[2][BN * BK];   // 2 x 8 KB, linear [col][k]

    const int tid = threadIdx.x;
    const int lane = tid & 63;
    const int w = tid >> 6;
    const int wm = w >> 1, wn = w & 1;
    const int ln = lane & 15, l4 = lane >> 4;

    // id = c*128 + m : m-sharing blocks are ≡ m (mod 8) -> same XCD L2.
    const int mb = blockIdx.x & 127;
    const int c = blockIdx.x >> 7;            // 0..9
    const int nb = (c >= 1) + (c >= 3) + (c >= 6);
    const int chunk = c - nb * (nb + 1) / 2;
    const int nbase = nb * BN;
    const int mbase = mb * BM;
    const int kbase = chunk * (KSTEPS * BK);

    f32x4 acc[2][4] = {};

    const int srow = tid >> 2;       // 0..63
    const int sk = (tid & 3) * 8;    // k offset (elements) of this thread's 16B

    auto stage = [&](int kk, int buf) {
        gll16(xb + (size_t)(mbase + srow) * DDIM + kk + sk, &As[buf][tid * 8]);
        gll16(WT + (size_t)(nbase + srow) * DDIM + kk + sk, &Bs[buf][tid * 8]);
        gll16(WT + (size_t)(nbase + 64 + srow) * DDIM + kk + sk, &Bs[buf][2048 + tid * 8]);
    };
    auto compute = [&](int buf) {
        short8 a[2], b[4];
#pragma unroll
        for (int m = 0; m < 2; ++m) {
            int row = wm * 32 + m * 16 + ln;
            a[m] = *reinterpret_cast<const short8*>(&As[buf][row * BK + l4 * 8]);
        }
#pragma unroll
        for (int n = 0; n < 4; ++n) {
            int col = wn * 64 + n * 16 + ln;
            b[n] = *reinterpret_cast<const short8*>(&Bs[buf][col * BK + l4 * 8]);
        }
#pragma unroll
        for (int m = 0; m < 2; ++m)
#pragma unroll
            for (int n = 0; n < 4; ++n)
                acc[m][n] = __builtin_amdgcn_mfma_f32_16x16x32_bf16(a[m], b[n], acc[m][n], 0, 0, 0);
    };

    stage(kbase, 0);
    __syncthreads();                       // buf0 ready
    stage(kbase + BK, 1);                  // t=1 in flight under compute(0)
    compute(0);
    __syncthreads();                       // buf1 ready, buf0 free
    stage(kbase + 2 * BK, 0);
    compute(1);
    __syncthreads();
    stage(kbase + 3 * BK, 1);
    compute(0);
    __syncthreads();
    compute(1);

    // epilogue: out[row] += sum_col y_partial[row][col] * xb[row][col]
#pragma unroll
    for (int m = 0; m < 2; ++m) {
#pragma unroll
        for (int q = 0; q < 4; ++q) {
            int grow = mbase + wm * 32 + m * 16 + l4 * 4 + q;   // C/D: row=(lane>>4)*4+reg
            float s = 0.f;
#pragma unroll
            for (int n = 0; n < 4; ++n) {
                int gcol = nbase + wn * 64 + n * 16 + ln;        // C/D: col=lane&15
                s += acc[m][n][q] * bf2f(xb[(size_t)grow * DDIM + gcol]);
            }
#pragma unroll
            for (int off = 1; off < 16; off <<= 1)
                s += __shfl_xor(s, off, 64);
            if (ln == 0) atomicAdd(out + grow, s);
        }
    }
}

extern "C" void kernel_launch(void* const* d_in, const int* in_sizes, int n_in,
                              void* d_out, int out_size, void* d_ws, size_t ws_size,
                              hipStream_t stream) {
    const float* x = (const float*)d_in[0];
    const float* kern = (const float*)d_in[1];
    const int* fd = (const int*)d_in[2];
    float* out = (float*)d_out;

    unsigned short* WT = (unsigned short*)d_ws;                      // 512 KB
    unsigned short* xb = WT + (size_t)DDIM * DDIM;                   // 8 MB

    dim3 wgrid(4, DDIM);
    w_kernel<<<wgrid, 256, 0, stream>>>(kern, fd, x, WT, xb, out);
    quad_kernel<<<1280, 256, 0, stream>>>(xb, WT, out);
}